// Round 5
// baseline (893.561 us; speedup 1.0000x reference)
//
#include <hip/hip_runtime.h>
#include <math.h>
#include <cstdint>

#define B_ 4
#define C_ 384
#define V_ 8
#define H_ 181
#define W_ 360
#define HW_ (H_*W_)      // 65160
#define NP_ (B_*HW_)     // 260640
#define HP_ (H_+4)       // 185
#define WP_ (W_+4)       // 364

// ------------------------------------------------------------------
// k_prep: vbias[o] = pw_b[o] + sum_c pw_w[o,c]*(bias[c]*ksum[c]+dwb[c])
//         kswt[c][12] = dwk[c][0..8]*scale[c] (padded to 12 -> 16B rows)
//         pwT[c][16]  = pw_w[o][c] transposed (contiguous per channel)
// ------------------------------------------------------------------
__global__ void k_prep(const float* __restrict__ scale,
                       const float* __restrict__ bias,
                       const float* __restrict__ dwk,
                       const float* __restrict__ dwb,
                       const float* __restrict__ pw_w,
                       const float* __restrict__ pw_b,
                       float* __restrict__ vbias,
                       float* __restrict__ kswt,
                       float* __restrict__ pwT) {
  __shared__ float sb[C_];
  int t = threadIdx.x;
  if (t < C_) {
    float ks = 0.f;
    float sc = scale[t];
#pragma unroll
    for (int k = 0; k < 9; ++k) {
      float kv = dwk[t * 9 + k];
      ks += kv;
      kswt[t * 12 + k] = kv * sc;
    }
    kswt[t * 12 + 9] = 0.f;
    kswt[t * 12 + 10] = 0.f;
    kswt[t * 12 + 11] = 0.f;
#pragma unroll
    for (int o = 0; o < 16; ++o) pwT[t * 16 + o] = pw_w[o * C_ + t];
    sb[t] = bias[t] * ks + dwb[t];
  }
  __syncthreads();
  if (t < 16) {
    float acc = pw_b[t];
    for (int c = 0; c < C_; ++c) acc = fmaf(pw_w[t * C_ + c], sb[c], acc);
    vbias[t] = acc;
  }
}

// ------------------------------------------------------------------
// k_stats: LN mean/rstd per pixel + fused down-proj (raw x, 1x1 C->8)
// ------------------------------------------------------------------
__global__ __launch_bounds__(256) void k_stats(
    const float* __restrict__ x, const float* __restrict__ down_w,
    const float* __restrict__ down_b, float* __restrict__ meanv,
    float* __restrict__ rstdv, float* __restrict__ proj) {
  int p = blockIdx.x * 256 + threadIdx.x;
  if (p >= NP_) return;
  int b = p / HW_, hw = p - b * HW_;
  const float* xp = x + (size_t)b * C_ * HW_ + hw;

  float sA = 0.f, sB = 0.f, s2A = 0.f, s2B = 0.f;
  float apA[8], apB[8];
#pragma unroll
  for (int j = 0; j < 8; ++j) { apA[j] = 0.f; apB[j] = 0.f; }

#pragma unroll 4
  for (int c = 0; c < C_ / 2; ++c) {
    float v0 = xp[(size_t)c * HW_];
    float v1 = xp[(size_t)(c + C_ / 2) * HW_];
    sA += v0;
    sB += v1;
    s2A = fmaf(v0, v0, s2A);
    s2B = fmaf(v1, v1, s2B);
#pragma unroll
    for (int j = 0; j < 8; ++j) {
      apA[j] = fmaf(v0, down_w[j * C_ + c], apA[j]);
      apB[j] = fmaf(v1, down_w[j * C_ + c + C_ / 2], apB[j]);
    }
  }
  float m = (sA + sB) * (1.0f / C_);
  float var = fmaf(-m, m, (s2A + s2B) * (1.0f / C_));
  var = var < 0.f ? 0.f : var;
  meanv[p] = m;
  rstdv[p] = rsqrtf(var + 1e-5f);
#pragma unroll
  for (int j = 0; j < 8; ++j)
    proj[((size_t)b * 8 + j) * HW_ + hw] = apA[j] + apB[j] + down_b[j];
}

// ------------------------------------------------------------------
// k_vel: LN apply + geo-pad depthwise 3x3 + 1x1 (C->16) velocity.
// 32x8 tile, 256 thr, CSPLIT=2 channel halves -> partials in d_out
// channels 352..383. Double-buffered LDS + 2-bank register prefetch,
// one barrier per 8-channel chunk.
// ------------------------------------------------------------------
#define TW 32
#define TH 8
#define HALO_W (TW + 2)          // 34
#define HALO_H (TH + 2)          // 10
#define NHALO (HALO_W * HALO_H)  // 340
#define KC 8
#define CSPLIT 2
#define CPB (C_ / CSPLIT)        // 192
#define NCHUNK (CPB / KC)        // 24
#define NTW ((W_ + TW - 1) / TW) // 12
#define NTH ((H_ + TH - 1) / TH) // 23

__device__ __forceinline__ int geo_off(int h0, int w0, int i) {
  int hy = i / HALO_W, hx = i - hy * HALO_W;
  int hh = h0 - 1 + hy;
  int ww = w0 - 1 + hx;
  int hs, sh = 0;
  if (hh < 0)        { hs = -1 - hh;         sh = 180; }
  else if (hh >= H_) { hs = 2 * H_ - 1 - hh; sh = 180; }
  else               { hs = hh; }
  int ws2 = ww + sh;
  ws2 = ((ws2 % W_) + W_) % W_;
  return hs * W_ + ws2;
}

__device__ __forceinline__ void loadc(const float* xc0, const float* xc1,
                                      bool has1, float pf[16]) {
#pragma unroll
  for (int cl = 0; cl < KC; ++cl) pf[cl] = xc0[(size_t)cl * HW_];
  if (has1) {
#pragma unroll
    for (int cl = 0; cl < KC; ++cl) pf[KC + cl] = xc1[(size_t)cl * HW_];
  }
}

__device__ __forceinline__ void stage(float (*__restrict__ xnb)[NHALO],
                                      const float pf[16], int i0, int i1,
                                      bool has1, float m0, float r0, float m1,
                                      float r1) {
#pragma unroll
  for (int cl = 0; cl < KC; ++cl) xnb[cl][i0] = (pf[cl] - m0) * r0;
  if (has1) {
#pragma unroll
    for (int cl = 0; cl < KC; ++cl) xnb[cl][i1] = (pf[KC + cl] - m1) * r1;
  }
}

__device__ __forceinline__ void compute_chunk(
    const float (*__restrict__ xnb)[NHALO], int cb,
    const float* __restrict__ kswt, const float* __restrict__ pwT, int ty,
    int tx, float acc[16]) {
#pragma unroll
  for (int cl = 0; cl < KC; ++cl) {
    int c = cb + cl;  // wave-uniform
    const float* kk = kswt + (size_t)c * 12;   // contiguous 48B row
    const float* pwc = pwT + (size_t)c * 16;   // contiguous 64B row
    float a = 0.f;
#pragma unroll
    for (int dy = 0; dy < 3; ++dy)
#pragma unroll
      for (int dx = 0; dx < 3; ++dx)
        a = fmaf(xnb[cl][(ty + dy) * HALO_W + tx + dx], kk[dy * 3 + dx], a);
#pragma unroll
    for (int o = 0; o < 16; ++o)
      acc[o] = fmaf(a, pwc[o], acc[o]);
  }
}

__global__ __launch_bounds__(256, 4) void k_vel(
    const float* __restrict__ x, const float* __restrict__ meanv,
    const float* __restrict__ rstdv, const float* __restrict__ kswt,
    const float* __restrict__ pwT, float* __restrict__ velout) {
  __shared__ float xn[2][KC][NHALO];

  int tid = threadIdx.x;
  int bx = blockIdx.x;
  int bw = bx % NTW; bx /= NTW;
  int bh = bx % NTH; bx /= NTH;
  int b  = bx % B_;
  int sl = bx / B_;
  int w0 = bw * TW, h0 = bh * TH;
  int cbase = sl * CPB;

  int i0 = tid, i1 = tid + 256;
  bool has1 = (i1 < NHALO);
  int o0 = geo_off(h0, w0, i0);
  int o1 = has1 ? geo_off(h0, w0, i1) : o0;

  size_t bHW = (size_t)b * HW_;
  float m0v = meanv[bHW + o0], r0v = rstdv[bHW + o0];
  float m1v = 0.f, r1v = 0.f;
  if (has1) { m1v = meanv[bHW + o1]; r1v = rstdv[bHW + o1]; }

  const float* xs0 = x + ((size_t)b * C_ + cbase) * HW_ + o0;
  const float* xs1 = x + ((size_t)b * C_ + cbase) * HW_ + o1;

  float pfA[16], pfB[16];
  loadc(xs0, xs1, has1, pfA);                              // chunk 0
  loadc(xs0 + (size_t)KC * HW_, xs1 + (size_t)KC * HW_, has1, pfB);  // chunk 1
  stage(xn[0], pfA, i0, i1, has1, m0v, r0v, m1v, r1v);
  __syncthreads();

  int tx = tid & 31, ty = tid >> 5;
  float acc[16];
#pragma unroll
  for (int o = 0; o < 16; ++o) acc[o] = 0.f;

#pragma unroll 1
  for (int k = 0; k < NCHUNK; k += 2) {
    // ---- even half: compute chunk k (buf0), stage k+1 (buf1) ----
    if (k + 2 < NCHUNK)
      loadc(xs0 + (size_t)(k + 2) * KC * HW_, xs1 + (size_t)(k + 2) * KC * HW_,
            has1, pfA);  // issue k+2 BEFORE waiting on pfB
    stage(xn[1], pfB, i0, i1, has1, m0v, r0v, m1v, r1v);
    compute_chunk(xn[0], cbase + k * KC, kswt, pwT, ty, tx, acc);
    __syncthreads();
    // ---- odd half: compute chunk k+1 (buf1), stage k+2 (buf0) ----
    if (k + 3 < NCHUNK)
      loadc(xs0 + (size_t)(k + 3) * KC * HW_, xs1 + (size_t)(k + 3) * KC * HW_,
            has1, pfB);
    if (k + 2 < NCHUNK)
      stage(xn[0], pfA, i0, i1, has1, m0v, r0v, m1v, r1v);
    compute_chunk(xn[1], cbase + (k + 1) * KC, kswt, pwT, ty, tx, acc);
    __syncthreads();
  }

  int hp = h0 + ty, wp = w0 + tx;
  if (hp < H_ && wp < W_) {
    int hw = hp * W_ + wp;
    // partial vel -> spare out channels: c = 352 + sl*16 + o
    float* dst = velout + ((size_t)b * C_ + 352 + sl * 16) * HW_ + hw;
#pragma unroll
    for (int o = 0; o < 16; ++o) dst[(size_t)o * HW_] = acc[o];
  }
}

// ------------------------------------------------------------------
// k_samp: departure points + bicubic geo-sample + 1x1 up (8->384).
// vel partials live in out channels 352..367 (half A) / 368..383 (B).
// ------------------------------------------------------------------
__device__ __forceinline__ void cubw(float t, float w[4]) {
  const float A = -0.75f;
  float t1 = t + 1.0f;
  w[0] = ((A * t1 - 5.0f * A) * t1 + 8.0f * A) * t1 - 4.0f * A;
  w[1] = ((A + 2.0f) * t - (A + 3.0f)) * t * t + 1.0f;
  float s = 1.0f - t;
  w[2] = ((A + 2.0f) * s - (A + 3.0f)) * s * s + 1.0f;
  float t2 = 2.0f - t;
  w[3] = ((A * t2 - 5.0f * A) * t2 + 8.0f * A) * t2 - 4.0f * A;
}

__global__ __launch_bounds__(256) void k_samp(
    const float* __restrict__ proj, const float* __restrict__ latg,
    const float* __restrict__ lonG, const float* __restrict__ dtp,
    const float* __restrict__ up_w, const float* __restrict__ up_b,
    const float* __restrict__ vbias, float* out) {
  int p = blockIdx.x * 256 + threadIdx.x;
  if (p >= NP_) return;
  int b = p / HW_, hw = p - b * HW_;

  const float TWO_PI = 6.28318530717958647692f;
  const float X_SCALE = 57.295779513082320877f;  // W/(2*pi)
  const float MIN_LAT = -1.57079632679489661923f;
  const float Y_SCALE = 57.295779513082320877f;  // (H-1)/pi

  float dt = dtp[0];
  float lat_p = latg[p];
  float lon_p = lonG[p];
  float sin_p, cos_p;
  sincosf(lat_p, &sin_p, &cos_p);

  float samp[V_];
  const float* projb = proj + (size_t)b * V_ * HW_;
  const float* velA = out + ((size_t)b * C_ + 352) * HW_ + hw;
  const float* velB = out + ((size_t)b * C_ + 368) * HW_ + hw;

  for (int vch = 0; vch < V_; ++vch) {
    float u  = velA[(size_t)vch * HW_] + velB[(size_t)vch * HW_] + vbias[vch];
    float vv = velA[(size_t)(8 + vch) * HW_] + velB[(size_t)(8 + vch) * HW_] +
               vbias[8 + vch];
    float lon_pr = -u * dt;
    float lat_pr = -vv * dt;
    float s_lp, c_lp, s_op, c_op;
    sincosf(lat_pr, &s_lp, &c_lp);
    sincosf(lon_pr, &s_op, &c_op);
    float sin_lat = s_lp * cos_p + c_lp * c_op * sin_p;
    sin_lat = fminf(fmaxf(sin_lat, -1.0f + 1e-7f), 1.0f - 1e-7f);
    float lat_dep = asinf(sin_lat);
    float num = c_lp * s_op;
    float den = c_lp * c_op * cos_p - s_lp * sin_p;
    float lon_dep = fmodf(lon_p + atan2f(num, den) + TWO_PI, TWO_PI);

    float xf = fmaf(lon_dep, X_SCALE, 2.0f);            // pix_x + PAD
    float yf = fmaf(lat_dep - MIN_LAT, Y_SCALE, 2.0f);  // pix_y + PAD

    float x0f = floorf(xf), txf = xf - x0f;
    float y0f = floorf(yf), tyf = yf - y0f;
    int ix0 = (int)x0f, iy0 = (int)y0f;
    float wx[4], wy[4];
    cubw(txf, wx);
    cubw(tyf, wy);

    const float* pv = projb + (size_t)vch * HW_;
    float acc = 0.f;
#pragma unroll
    for (int i = 0; i < 4; ++i) {
      int yi = iy0 - 1 + i;
      yi = yi < 0 ? 0 : (yi > HP_ - 1 ? HP_ - 1 : yi);
      int hh = yi - 2;
      int hs, sh = 0;
      if (hh < 0)        { hs = -1 - hh;         sh = 1; }
      else if (hh >= H_) { hs = 2 * H_ - 1 - hh; sh = 1; }
      else               { hs = hh; }
      const float* row = pv + hs * W_;
      int shoff = sh ? 180 : 0;
      float r = 0.f;
#pragma unroll
      for (int j = 0; j < 4; ++j) {
        int xi = ix0 - 1 + j;
        xi = xi < 0 ? 0 : (xi > WP_ - 1 ? WP_ - 1 : xi);
        int ww = xi - 2 + shoff;
        ww = ((ww % W_) + W_) % W_;
        r = fmaf(row[ww], wx[j], r);
      }
      acc = fmaf(r, wy[i], acc);
    }
    samp[vch] = acc;  // proj already includes down_b
  }

  float* ob = out + (size_t)b * C_ * HW_ + hw;
  for (int c = 0; c < C_; ++c) {
    const float* uw = up_w + c * V_;
    float o = up_b[c];
#pragma unroll
    for (int v = 0; v < V_; ++v) o = fmaf(samp[v], uw[v], o);
    ob[(size_t)c * HW_] = o;
  }
}

// ------------------------------------------------------------------
extern "C" void kernel_launch(void* const* d_in, const int* in_sizes, int n_in,
                              void* d_out, int out_size, void* d_ws,
                              size_t ws_size, hipStream_t stream) {
  const float* hidden = (const float*)d_in[0];
  const float* latg   = (const float*)d_in[1];
  const float* lonG   = (const float*)d_in[2];
  const float* dtp    = (const float*)d_in[3];
  const float* nsc    = (const float*)d_in[4];
  const float* nbi    = (const float*)d_in[5];
  const float* dwk    = (const float*)d_in[6];
  const float* dwb    = (const float*)d_in[7];
  const float* pw_w   = (const float*)d_in[8];
  const float* pw_b   = (const float*)d_in[9];
  const float* down_w = (const float*)d_in[10];
  const float* down_b = (const float*)d_in[11];
  const float* up_w   = (const float*)d_in[12];
  const float* up_b   = (const float*)d_in[13];
  float* out = (float*)d_out;

  float* ws    = (float*)d_ws;
  float* meanv = ws;                       // NP_
  float* rstdv = ws + NP_;                 // NP_
  float* proj  = ws + 2 * (size_t)NP_;     // 8*NP_
  float* vbias = ws + 10 * (size_t)NP_;    // 16
  float* kswt  = vbias + 16;               // 12*C_
  float* pwT   = kswt + 12 * C_;           // 16*C_

  int nblk = (NP_ + 255) / 256;
  hipLaunchKernelGGL(k_prep, dim3(1), dim3(C_), 0, stream, nsc, nbi, dwk, dwb,
                     pw_w, pw_b, vbias, kswt, pwT);
  hipLaunchKernelGGL(k_stats, dim3(nblk), dim3(256), 0, stream, hidden, down_w,
                     down_b, meanv, rstdv, proj);
  hipLaunchKernelGGL(k_vel, dim3(NTW * NTH * B_ * CSPLIT), dim3(256), 0,
                     stream, hidden, meanv, rstdv, kswt, pwT, out);
  hipLaunchKernelGGL(k_samp, dim3(nblk), dim3(256), 0, stream, proj, latg,
                     lonG, dtp, up_w, up_b, vbias, out);
}

// Round 6
// 570.635 us; speedup vs baseline: 1.5659x; 1.5659x over previous
//
#include <hip/hip_runtime.h>
#include <math.h>
#include <cstdint>

#define B_ 4
#define C_ 384
#define V_ 8
#define H_ 181
#define W_ 360
#define HW_ (H_*W_)      // 65160
#define NP_ (B_*HW_)     // 260640
#define HP_ (H_+4)       // 185
#define WP_ (W_+4)       // 364

typedef float f32x2 __attribute__((ext_vector_type(2)));

// ------------------------------------------------------------------
// k_prep: fold biases; build pair-interleaved weight tables:
//   kswt2[pair][tap][2] = dwk*scale     (192 pairs x 9 x 2)
//   pwT2 [pair][o][2]   = pw_w[o][c]    (192 x 16 x 2)
//   upT2 [pair][v][2]   = up_w[c][v]    (192 x 8 x 2)
// ------------------------------------------------------------------
__global__ void k_prep(const float* __restrict__ scale,
                       const float* __restrict__ bias,
                       const float* __restrict__ dwk,
                       const float* __restrict__ dwb,
                       const float* __restrict__ pw_w,
                       const float* __restrict__ pw_b,
                       const float* __restrict__ up_w,
                       float* __restrict__ vbias,
                       float* __restrict__ kswt2,
                       float* __restrict__ pwT2,
                       float* __restrict__ upT2) {
  __shared__ float sb[C_];
  int t = threadIdx.x;
  if (t < C_) {
    float ks = 0.f;
    float sc = scale[t];
    int pr = t >> 1, lo = t & 1;
#pragma unroll
    for (int k = 0; k < 9; ++k) {
      float kv = dwk[t * 9 + k];
      ks += kv;
      kswt2[pr * 18 + k * 2 + lo] = kv * sc;
    }
#pragma unroll
    for (int o = 0; o < 16; ++o) pwT2[pr * 32 + o * 2 + lo] = pw_w[o * C_ + t];
#pragma unroll
    for (int v = 0; v < 8; ++v) upT2[pr * 16 + v * 2 + lo] = up_w[t * V_ + v];
    sb[t] = bias[t] * ks + dwb[t];
  }
  __syncthreads();
  if (t < 16) {
    float acc = pw_b[t];
    for (int c = 0; c < C_; ++c) acc = fmaf(pw_w[t * C_ + c], sb[c], acc);
    vbias[t] = acc;
  }
}

// ------------------------------------------------------------------
// k_stats: LN mean/rstd per pixel + fused down-proj (raw x, 1x1 C->8)
// ------------------------------------------------------------------
__global__ __launch_bounds__(256) void k_stats(
    const float* __restrict__ x, const float* __restrict__ down_w,
    const float* __restrict__ down_b, float* __restrict__ meanv,
    float* __restrict__ rstdv, float* __restrict__ proj) {
  int p = blockIdx.x * 256 + threadIdx.x;
  if (p >= NP_) return;
  int b = p / HW_, hw = p - b * HW_;
  const float* xp = x + (size_t)b * C_ * HW_ + hw;

  float sA = 0.f, sB = 0.f, s2A = 0.f, s2B = 0.f;
  float apA[8], apB[8];
#pragma unroll
  for (int j = 0; j < 8; ++j) { apA[j] = 0.f; apB[j] = 0.f; }

#pragma unroll 4
  for (int c = 0; c < C_ / 2; ++c) {
    float v0 = xp[(size_t)c * HW_];
    float v1 = xp[(size_t)(c + C_ / 2) * HW_];
    sA += v0;
    sB += v1;
    s2A = fmaf(v0, v0, s2A);
    s2B = fmaf(v1, v1, s2B);
#pragma unroll
    for (int j = 0; j < 8; ++j) {
      apA[j] = fmaf(v0, down_w[j * C_ + c], apA[j]);
      apB[j] = fmaf(v1, down_w[j * C_ + c + C_ / 2], apB[j]);
    }
  }
  float m = (sA + sB) * (1.0f / C_);
  float var = fmaf(-m, m, (s2A + s2B) * (1.0f / C_));
  var = var < 0.f ? 0.f : var;
  meanv[p] = m;
  rstdv[p] = rsqrtf(var + 1e-5f);
#pragma unroll
  for (int j = 0; j < 8; ++j)
    proj[((size_t)b * 8 + j) * HW_ + hw] = apA[j] + apB[j] + down_b[j];
}

// ------------------------------------------------------------------
// k_vel: LN apply + geo-pad depthwise 3x3 + 1x1 (C->16) velocity.
// Round-3 skeleton (32x8 tile, 256 thr, reg prefetch, 2 barriers/chunk)
// with channel-PAIRED packed-f32 math (v_pk_fma_f32 via elementwise_fma)
// and float2 LDS cells (ds_read_b64).
// ------------------------------------------------------------------
#define TW 32
#define TH 8
#define HALO_W (TW + 2)          // 34
#define HALO_H (TH + 2)          // 10
#define NHALO (HALO_W * HALO_H)  // 340
#define KP 8                      // channel PAIRS per chunk (16 channels)
#define KC (2*KP)
#define NCHUNK (C_ / KC)         // 24
#define NTW ((W_ + TW - 1) / TW) // 12
#define NTH ((H_ + TH - 1) / TH) // 23

__device__ __forceinline__ int geo_off(int h0, int w0, int i) {
  int hy = i / HALO_W, hx = i - hy * HALO_W;
  int hh = h0 - 1 + hy;
  int ww = w0 - 1 + hx;
  int hs, sh = 0;
  if (hh < 0)        { hs = -1 - hh;         sh = 180; }
  else if (hh >= H_) { hs = 2 * H_ - 1 - hh; sh = 180; }
  else               { hs = hh; }
  int ws2 = ww + sh;
  ws2 = ((ws2 % W_) + W_) % W_;
  return hs * W_ + ws2;
}

__global__ __launch_bounds__(256) void k_vel(
    const float* __restrict__ x, const float* __restrict__ meanv,
    const float* __restrict__ rstdv, const float* __restrict__ kswt2,
    const float* __restrict__ pwT2, float* __restrict__ vel) {
  __shared__ f32x2 xn[KP][NHALO];

  int tid = threadIdx.x;
  int bx = blockIdx.x;
  int bw = bx % NTW; bx /= NTW;
  int bh = bx % NTH;
  int b  = bx / NTH;
  int w0 = bw * TW, h0 = bh * TH;

  int i0 = tid, i1 = tid + 256;
  bool has1 = (i1 < NHALO);
  int o0 = geo_off(h0, w0, i0);
  int o1 = has1 ? geo_off(h0, w0, i1) : o0;

  size_t bHW = (size_t)b * HW_;
  float r0v = rstdv[bHW + o0];
  float n0v = -meanv[bHW + o0] * r0v;  // xn = x*r + n
  float r1v = 0.f, n1v = 0.f;
  if (has1) { r1v = rstdv[bHW + o1]; n1v = -meanv[bHW + o1] * r1v; }
  f32x2 r0P = {r0v, r0v}, n0P = {n0v, n0v};
  f32x2 r1P = {r1v, r1v}, n1P = {n1v, n1v};

  const float* xb0 = x + (size_t)b * C_ * HW_ + o0;
  const float* xb1 = x + (size_t)b * C_ * HW_ + o1;

  f32x2 pf0[KP], pf1[KP];
#pragma unroll
  for (int k = 0; k < KP; ++k) {
    pf0[k].x = xb0[(size_t)(2 * k) * HW_];
    pf0[k].y = xb0[(size_t)(2 * k + 1) * HW_];
  }
  if (has1) {
#pragma unroll
    for (int k = 0; k < KP; ++k) {
      pf1[k].x = xb1[(size_t)(2 * k) * HW_];
      pf1[k].y = xb1[(size_t)(2 * k + 1) * HW_];
    }
  }

  int tx = tid & 31, ty = tid >> 5;
  f32x2 accP[16];
#pragma unroll
  for (int o = 0; o < 16; ++o) accP[o] = f32x2{0.f, 0.f};

  const f32x2* kk2 = (const f32x2*)kswt2;  // [pair*9 + tap]
  const f32x2* pw2 = (const f32x2*)pwT2;   // [pair*16 + o]

#pragma unroll 1
  for (int chunk = 0; chunk < NCHUNK; ++chunk) {
    // stage (normalized pairs) into LDS from prefetch registers
#pragma unroll
    for (int k = 0; k < KP; ++k)
      xn[k][i0] = __builtin_elementwise_fma(pf0[k], r0P, n0P);
    if (has1) {
#pragma unroll
      for (int k = 0; k < KP; ++k)
        xn[k][i1] = __builtin_elementwise_fma(pf1[k], r1P, n1P);
    }
    __syncthreads();

    // issue next chunk's loads; consumed at next stage phase
    if (chunk + 1 < NCHUNK) {
      const float* xc0 = xb0 + (size_t)(chunk + 1) * KC * HW_;
#pragma unroll
      for (int k = 0; k < KP; ++k) {
        pf0[k].x = xc0[(size_t)(2 * k) * HW_];
        pf0[k].y = xc0[(size_t)(2 * k + 1) * HW_];
      }
      if (has1) {
        const float* xc1 = xb1 + (size_t)(chunk + 1) * KC * HW_;
#pragma unroll
        for (int k = 0; k < KP; ++k) {
          pf1[k].x = xc1[(size_t)(2 * k) * HW_];
          pf1[k].y = xc1[(size_t)(2 * k + 1) * HW_];
        }
      }
    }

    // compute on current chunk (channel pairs, packed fma)
    int pc0 = chunk * KP;
#pragma unroll
    for (int kp = 0; kp < KP; ++kp) {
      const f32x2* kk = kk2 + (size_t)(pc0 + kp) * 9;   // wave-uniform
      const f32x2* pw = pw2 + (size_t)(pc0 + kp) * 16;  // wave-uniform
      f32x2 aP = {0.f, 0.f};
#pragma unroll
      for (int dy = 0; dy < 3; ++dy)
#pragma unroll
        for (int dx = 0; dx < 3; ++dx)
          aP = __builtin_elementwise_fma(xn[kp][(ty + dy) * HALO_W + tx + dx],
                                         kk[dy * 3 + dx], aP);
#pragma unroll
      for (int o = 0; o < 16; ++o)
        accP[o] = __builtin_elementwise_fma(aP, pw[o], accP[o]);
    }
    __syncthreads();
  }

  int hp = h0 + ty, wp = w0 + tx;
  if (hp < H_ && wp < W_) {
    int hw = hp * W_ + wp;
#pragma unroll
    for (int o = 0; o < 16; ++o)
      vel[((size_t)b * 16 + o) * HW_ + hw] = accP[o].x + accP[o].y;
  }
}

// ------------------------------------------------------------------
// k_samp: departure points + bicubic geo-sample + packed 1x1 up (8->384)
// ------------------------------------------------------------------
__device__ __forceinline__ void cubw(float t, float w[4]) {
  const float A = -0.75f;
  float t1 = t + 1.0f;
  w[0] = ((A * t1 - 5.0f * A) * t1 + 8.0f * A) * t1 - 4.0f * A;
  w[1] = ((A + 2.0f) * t - (A + 3.0f)) * t * t + 1.0f;
  float s = 1.0f - t;
  w[2] = ((A + 2.0f) * s - (A + 3.0f)) * s * s + 1.0f;
  float t2 = 2.0f - t;
  w[3] = ((A * t2 - 5.0f * A) * t2 + 8.0f * A) * t2 - 4.0f * A;
}

__global__ __launch_bounds__(256) void k_samp(
    const float* __restrict__ vel, const float* __restrict__ proj,
    const float* __restrict__ latg, const float* __restrict__ lonG,
    const float* __restrict__ dtp, const float* __restrict__ upT2,
    const float* __restrict__ up_b, const float* __restrict__ vbias,
    float* __restrict__ out) {
  int p = blockIdx.x * 256 + threadIdx.x;
  if (p >= NP_) return;
  int b = p / HW_, hw = p - b * HW_;

  const float TWO_PI = 6.28318530717958647692f;
  const float X_SCALE = 57.295779513082320877f;  // W/(2*pi)
  const float MIN_LAT = -1.57079632679489661923f;
  const float Y_SCALE = 57.295779513082320877f;  // (H-1)/pi

  float dt = dtp[0];
  float lat_p = latg[p];
  float lon_p = lonG[p];
  float sin_p, cos_p;
  sincosf(lat_p, &sin_p, &cos_p);

  f32x2 s2[V_];
  const float* projb = proj + (size_t)b * V_ * HW_;

  for (int vch = 0; vch < V_; ++vch) {
    float u  = vel[((size_t)b * 16 + vch) * HW_ + hw] + vbias[vch];
    float vv = vel[((size_t)b * 16 + 8 + vch) * HW_ + hw] + vbias[8 + vch];
    float lon_pr = -u * dt;
    float lat_pr = -vv * dt;
    float s_lp, c_lp, s_op, c_op;
    sincosf(lat_pr, &s_lp, &c_lp);
    sincosf(lon_pr, &s_op, &c_op);
    float sin_lat = s_lp * cos_p + c_lp * c_op * sin_p;
    sin_lat = fminf(fmaxf(sin_lat, -1.0f + 1e-7f), 1.0f - 1e-7f);
    float lat_dep = asinf(sin_lat);
    float num = c_lp * s_op;
    float den = c_lp * c_op * cos_p - s_lp * sin_p;
    float lon_dep = fmodf(lon_p + atan2f(num, den) + TWO_PI, TWO_PI);

    float xf = fmaf(lon_dep, X_SCALE, 2.0f);            // pix_x + PAD
    float yf = fmaf(lat_dep - MIN_LAT, Y_SCALE, 2.0f);  // pix_y + PAD

    float x0f = floorf(xf), txf = xf - x0f;
    float y0f = floorf(yf), tyf = yf - y0f;
    int ix0 = (int)x0f, iy0 = (int)y0f;
    float wx[4], wy[4];
    cubw(txf, wx);
    cubw(tyf, wy);

    const float* pv = projb + (size_t)vch * HW_;
    float acc = 0.f;
#pragma unroll
    for (int i = 0; i < 4; ++i) {
      int yi = iy0 - 1 + i;
      yi = yi < 0 ? 0 : (yi > HP_ - 1 ? HP_ - 1 : yi);
      int hh = yi - 2;
      int hs, sh = 0;
      if (hh < 0)        { hs = -1 - hh;         sh = 1; }
      else if (hh >= H_) { hs = 2 * H_ - 1 - hh; sh = 1; }
      else               { hs = hh; }
      const float* row = pv + hs * W_;
      int shoff = sh ? 180 : 0;
      float r = 0.f;
#pragma unroll
      for (int j = 0; j < 4; ++j) {
        int xi = ix0 - 1 + j;
        xi = xi < 0 ? 0 : (xi > WP_ - 1 ? WP_ - 1 : xi);
        int ww = xi - 2 + shoff;
        ww = ((ww % W_) + W_) % W_;
        r = fmaf(row[ww], wx[j], r);
      }
      acc = fmaf(r, wy[i], acc);
    }
    s2[vch] = f32x2{acc, acc};  // proj already includes down_b
  }

  // packed up-conv: 2 output channels per iteration
  float* ob = out + (size_t)b * C_ * HW_ + hw;
  const f32x2* up2 = (const f32x2*)upT2;        // [pair*8 + v]
  const f32x2* ub2 = (const f32x2*)up_b;        // pairs of biases
  for (int i = 0; i < C_ / 2; ++i) {
    f32x2 o2 = ub2[i];
    const f32x2* uw = up2 + (size_t)i * 8;
#pragma unroll
    for (int v = 0; v < V_; ++v) o2 = __builtin_elementwise_fma(s2[v], uw[v], o2);
    ob[(size_t)(2 * i) * HW_] = o2.x;
    ob[(size_t)(2 * i + 1) * HW_] = o2.y;
  }
}

// ------------------------------------------------------------------
extern "C" void kernel_launch(void* const* d_in, const int* in_sizes, int n_in,
                              void* d_out, int out_size, void* d_ws,
                              size_t ws_size, hipStream_t stream) {
  const float* hidden = (const float*)d_in[0];
  const float* latg   = (const float*)d_in[1];
  const float* lonG   = (const float*)d_in[2];
  const float* dtp    = (const float*)d_in[3];
  const float* nsc    = (const float*)d_in[4];
  const float* nbi    = (const float*)d_in[5];
  const float* dwk    = (const float*)d_in[6];
  const float* dwb    = (const float*)d_in[7];
  const float* pw_w   = (const float*)d_in[8];
  const float* pw_b   = (const float*)d_in[9];
  const float* down_w = (const float*)d_in[10];
  const float* down_b = (const float*)d_in[11];
  const float* up_w   = (const float*)d_in[12];
  const float* up_b   = (const float*)d_in[13];
  float* out = (float*)d_out;

  float* ws    = (float*)d_ws;
  float* meanv = ws;                       // NP_
  float* rstdv = ws + NP_;                 // NP_
  float* vel   = ws + 2 * (size_t)NP_;     // 16*NP_
  float* proj  = ws + 18 * (size_t)NP_;    // 8*NP_
  float* vbias = ws + 26 * (size_t)NP_;    // 16
  float* kswt2 = vbias + 16;               // 192*18 = 3456
  float* pwT2  = kswt2 + 192 * 18;         // 192*32 = 6144
  float* upT2  = pwT2 + 192 * 32;          // 192*16 = 3072

  int nblk = (NP_ + 255) / 256;
  hipLaunchKernelGGL(k_prep, dim3(1), dim3(C_), 0, stream, nsc, nbi, dwk, dwb,
                     pw_w, pw_b, up_w, vbias, kswt2, pwT2, upT2);
  hipLaunchKernelGGL(k_stats, dim3(nblk), dim3(256), 0, stream, hidden, down_w,
                     down_b, meanv, rstdv, proj);
  hipLaunchKernelGGL(k_vel, dim3(NTW * NTH * B_), dim3(256), 0, stream, hidden,
                     meanv, rstdv, kswt2, pwT2, vel);
  hipLaunchKernelGGL(k_samp, dim3(nblk), dim3(256), 0, stream, vel, proj, latg,
                     lonG, dtp, upT2, up_b, vbias, out);
}

// Round 7
// 532.631 us; speedup vs baseline: 1.6776x; 1.0714x over previous
//
#include <hip/hip_runtime.h>
#include <math.h>
#include <cstdint>

#define B_ 4
#define C_ 384
#define V_ 8
#define H_ 181
#define W_ 360
#define HW_ (H_*W_)      // 65160
#define NP_ (B_*HW_)     // 260640
#define HP_ (H_+4)       // 185
#define WP_ (W_+4)       // 364

typedef float f32x2 __attribute__((ext_vector_type(2)));

// ------------------------------------------------------------------
// k_prep: fold biases; pair-interleaved weight tables:
//   kswt2[pair][tap][2] = dwk*scale, pwT2[pair][o][2] = pw_w[o][c],
//   upT2[pair][v][2] = up_w[c][v]
// ------------------------------------------------------------------
__global__ void k_prep(const float* __restrict__ scale,
                       const float* __restrict__ bias,
                       const float* __restrict__ dwk,
                       const float* __restrict__ dwb,
                       const float* __restrict__ pw_w,
                       const float* __restrict__ pw_b,
                       const float* __restrict__ up_w,
                       float* __restrict__ vbias,
                       float* __restrict__ kswt2,
                       float* __restrict__ pwT2,
                       float* __restrict__ upT2) {
  __shared__ float sb[C_];
  int t = threadIdx.x;
  if (t < C_) {
    float ks = 0.f;
    float sc = scale[t];
    int pr = t >> 1, lo = t & 1;
#pragma unroll
    for (int k = 0; k < 9; ++k) {
      float kv = dwk[t * 9 + k];
      ks += kv;
      kswt2[pr * 18 + k * 2 + lo] = kv * sc;
    }
#pragma unroll
    for (int o = 0; o < 16; ++o) pwT2[pr * 32 + o * 2 + lo] = pw_w[o * C_ + t];
#pragma unroll
    for (int v = 0; v < 8; ++v) upT2[pr * 16 + v * 2 + lo] = up_w[t * V_ + v];
    sb[t] = bias[t] * ks + dwb[t];
  }
  __syncthreads();
  if (t < 16) {
    float acc = pw_b[t];
    for (int c = 0; c < C_; ++c) acc = fmaf(pw_w[t * C_ + c], sb[c], acc);
    vbias[t] = acc;
  }
}

// ------------------------------------------------------------------
// k_stats: LN mean/rstd per pixel + fused down-proj (raw x, 1x1 C->8)
// ------------------------------------------------------------------
__global__ __launch_bounds__(256) void k_stats(
    const float* __restrict__ x, const float* __restrict__ down_w,
    const float* __restrict__ down_b, float* __restrict__ meanv,
    float* __restrict__ rstdv, float* __restrict__ proj) {
  int p = blockIdx.x * 256 + threadIdx.x;
  if (p >= NP_) return;
  int b = p / HW_, hw = p - b * HW_;
  const float* xp = x + (size_t)b * C_ * HW_ + hw;

  float sA = 0.f, sB = 0.f, s2A = 0.f, s2B = 0.f;
  float apA[8], apB[8];
#pragma unroll
  for (int j = 0; j < 8; ++j) { apA[j] = 0.f; apB[j] = 0.f; }

#pragma unroll 4
  for (int c = 0; c < C_ / 2; ++c) {
    float v0 = xp[(size_t)c * HW_];
    float v1 = xp[(size_t)(c + C_ / 2) * HW_];
    sA += v0;
    sB += v1;
    s2A = fmaf(v0, v0, s2A);
    s2B = fmaf(v1, v1, s2B);
#pragma unroll
    for (int j = 0; j < 8; ++j) {
      apA[j] = fmaf(v0, down_w[j * C_ + c], apA[j]);
      apB[j] = fmaf(v1, down_w[j * C_ + c + C_ / 2], apB[j]);
    }
  }
  float m = (sA + sB) * (1.0f / C_);
  float var = fmaf(-m, m, (s2A + s2B) * (1.0f / C_));
  var = var < 0.f ? 0.f : var;
  meanv[p] = m;
  rstdv[p] = rsqrtf(var + 1e-5f);
#pragma unroll
  for (int j = 0; j < 8; ++j)
    proj[((size_t)b * 8 + j) * HW_ + hw] = apA[j] + apB[j] + down_b[j];
}

// ------------------------------------------------------------------
// k_vel: LN apply + geo-pad depthwise 3x3 + 1x1 (C->16) velocity.
// ONE WAVE PER BLOCK, private 16x4 tile + 18x6 halo in own LDS slice.
// ZERO barriers (per-wave DS ops are in-order). Packed-f32 math.
// Bijective XCD swizzle for halo L2 sharing.
// ------------------------------------------------------------------
#define WTW 16
#define WTH 4
#define WHW 18                    // halo width
#define WHH 6                     // halo height
#define WNH (WHW*WHH)             // 108 halo cells
#define KP 8                      // channel pairs per chunk (16 ch)
#define KC (2*KP)
#define NCHUNK (C_ / KC)          // 24
#define NTW2 ((W_ + WTW - 1) / WTW)  // 23
#define NTH2 ((H_ + WTH - 1) / WTH)  // 46
#define NWG_VEL (NTW2 * NTH2 * B_)   // 4232

__device__ __forceinline__ int geo_off_w(int h0, int w0, int i) {
  int hy = i / WHW, hx = i - hy * WHW;
  int hh = h0 - 1 + hy;
  int ww = w0 - 1 + hx;
  int hs, sh = 0;
  if (hh < 0)        { hs = -1 - hh;         sh = 180; }
  else if (hh >= H_) { hs = 2 * H_ - 1 - hh; sh = 180; }
  else               { hs = hh; }
  int ws2 = ww + sh;
  ws2 = ((ws2 % W_) + W_) % W_;
  return hs * W_ + ws2;
}

__global__ __launch_bounds__(64) void k_vel(
    const float* __restrict__ x, const float* __restrict__ meanv,
    const float* __restrict__ rstdv, const float* __restrict__ kswt2,
    const float* __restrict__ pwT2, float* __restrict__ vel) {
  __shared__ f32x2 xn[KP][WNH];

  int lane = threadIdx.x;
  // bijective XCD-aware remap (m204 formula)
  int bid = blockIdx.x;
  const int q = NWG_VEL / 8, r = NWG_VEL % 8;
  int xcd = bid & 7, idx = bid >> 3;
  int wg = (xcd < r ? xcd * (q + 1) : r * (q + 1) + (xcd - r) * q) + idx;
  int bw = wg % NTW2; wg /= NTW2;
  int bh = wg % NTH2;
  int b  = wg / NTH2;
  int w0 = bw * WTW, h0 = bh * WTH;

  int i0 = lane, i1 = lane + 64;
  bool has1 = (i1 < WNH);  // lanes 0..43
  int o0 = geo_off_w(h0, w0, i0);
  int o1 = has1 ? geo_off_w(h0, w0, i1) : o0;

  size_t bHW = (size_t)b * HW_;
  float r0v = rstdv[bHW + o0];
  float n0v = -meanv[bHW + o0] * r0v;  // xn = x*r + n
  float r1v = 0.f, n1v = 0.f;
  if (has1) { r1v = rstdv[bHW + o1]; n1v = -meanv[bHW + o1] * r1v; }
  f32x2 r0P = {r0v, r0v}, n0P = {n0v, n0v};
  f32x2 r1P = {r1v, r1v}, n1P = {n1v, n1v};

  const float* xb0 = x + (size_t)b * C_ * HW_ + o0;
  const float* xb1 = x + (size_t)b * C_ * HW_ + o1;

  f32x2 pf0[KP], pf1[KP];
#pragma unroll
  for (int k = 0; k < KP; ++k) {
    pf0[k].x = xb0[(size_t)(2 * k) * HW_];
    pf0[k].y = xb0[(size_t)(2 * k + 1) * HW_];
  }
  if (has1) {
#pragma unroll
    for (int k = 0; k < KP; ++k) {
      pf1[k].x = xb1[(size_t)(2 * k) * HW_];
      pf1[k].y = xb1[(size_t)(2 * k + 1) * HW_];
    }
  }

  int tx = lane & 15, ty = lane >> 4;
  f32x2 accP[16];
#pragma unroll
  for (int o = 0; o < 16; ++o) accP[o] = f32x2{0.f, 0.f};

  const f32x2* kk2 = (const f32x2*)kswt2;  // [pair*9 + tap]
  const f32x2* pw2 = (const f32x2*)pwT2;   // [pair*16 + o]

#pragma unroll 1
  for (int chunk = 0; chunk < NCHUNK; ++chunk) {
    // stage normalized pairs into this wave's private LDS (no barrier:
    // same-wave DS ops are in-order; WAR vs previous chunk's reads safe)
#pragma unroll
    for (int k = 0; k < KP; ++k)
      xn[k][i0] = __builtin_elementwise_fma(pf0[k], r0P, n0P);
    if (has1) {
#pragma unroll
      for (int k = 0; k < KP; ++k)
        xn[k][i1] = __builtin_elementwise_fma(pf1[k], r1P, n1P);
    }

    // issue next chunk's global loads; consumed next iteration
    if (chunk + 1 < NCHUNK) {
      const float* xc0 = xb0 + (size_t)(chunk + 1) * KC * HW_;
#pragma unroll
      for (int k = 0; k < KP; ++k) {
        pf0[k].x = xc0[(size_t)(2 * k) * HW_];
        pf0[k].y = xc0[(size_t)(2 * k + 1) * HW_];
      }
      if (has1) {
        const float* xc1 = xb1 + (size_t)(chunk + 1) * KC * HW_;
#pragma unroll
        for (int k = 0; k < KP; ++k) {
          pf1[k].x = xc1[(size_t)(2 * k) * HW_];
          pf1[k].y = xc1[(size_t)(2 * k + 1) * HW_];
        }
      }
    }

    // compute this chunk (channel pairs, packed fma)
    int pc0 = chunk * KP;
#pragma unroll
    for (int kp = 0; kp < KP; ++kp) {
      const f32x2* kk = kk2 + (size_t)(pc0 + kp) * 9;   // wave-uniform
      const f32x2* pw = pw2 + (size_t)(pc0 + kp) * 16;  // wave-uniform
      f32x2 aP = {0.f, 0.f};
#pragma unroll
      for (int dy = 0; dy < 3; ++dy)
#pragma unroll
        for (int dx = 0; dx < 3; ++dx)
          aP = __builtin_elementwise_fma(xn[kp][(ty + dy) * WHW + tx + dx],
                                         kk[dy * 3 + dx], aP);
#pragma unroll
      for (int o = 0; o < 16; ++o)
        accP[o] = __builtin_elementwise_fma(aP, pw[o], accP[o]);
    }
  }

  int hp = h0 + ty, wp = w0 + tx;
  if (hp < H_ && wp < W_) {
    int hw = hp * W_ + wp;
#pragma unroll
    for (int o = 0; o < 16; ++o)
      vel[((size_t)b * 16 + o) * HW_ + hw] = accP[o].x + accP[o].y;
  }
}

// ------------------------------------------------------------------
// k_samp: departure points + bicubic geo-sample + packed 1x1 up (8->384)
// ------------------------------------------------------------------
__device__ __forceinline__ void cubw(float t, float w[4]) {
  const float A = -0.75f;
  float t1 = t + 1.0f;
  w[0] = ((A * t1 - 5.0f * A) * t1 + 8.0f * A) * t1 - 4.0f * A;
  w[1] = ((A + 2.0f) * t - (A + 3.0f)) * t * t + 1.0f;
  float s = 1.0f - t;
  w[2] = ((A + 2.0f) * s - (A + 3.0f)) * s * s + 1.0f;
  float t2 = 2.0f - t;
  w[3] = ((A * t2 - 5.0f * A) * t2 + 8.0f * A) * t2 - 4.0f * A;
}

__global__ __launch_bounds__(256) void k_samp(
    const float* __restrict__ vel, const float* __restrict__ proj,
    const float* __restrict__ latg, const float* __restrict__ lonG,
    const float* __restrict__ dtp, const float* __restrict__ upT2,
    const float* __restrict__ up_b, const float* __restrict__ vbias,
    float* __restrict__ out) {
  int p = blockIdx.x * 256 + threadIdx.x;
  if (p >= NP_) return;
  int b = p / HW_, hw = p - b * HW_;

  const float TWO_PI = 6.28318530717958647692f;
  const float X_SCALE = 57.295779513082320877f;  // W/(2*pi)
  const float MIN_LAT = -1.57079632679489661923f;
  const float Y_SCALE = 57.295779513082320877f;  // (H-1)/pi

  float dt = dtp[0];
  float lat_p = latg[p];
  float lon_p = lonG[p];
  float sin_p, cos_p;
  sincosf(lat_p, &sin_p, &cos_p);

  f32x2 s2[V_];
  const float* projb = proj + (size_t)b * V_ * HW_;

  for (int vch = 0; vch < V_; ++vch) {
    float u  = vel[((size_t)b * 16 + vch) * HW_ + hw] + vbias[vch];
    float vv = vel[((size_t)b * 16 + 8 + vch) * HW_ + hw] + vbias[8 + vch];
    float lon_pr = -u * dt;
    float lat_pr = -vv * dt;
    float s_lp, c_lp, s_op, c_op;
    sincosf(lat_pr, &s_lp, &c_lp);
    sincosf(lon_pr, &s_op, &c_op);
    float sin_lat = s_lp * cos_p + c_lp * c_op * sin_p;
    sin_lat = fminf(fmaxf(sin_lat, -1.0f + 1e-7f), 1.0f - 1e-7f);
    float lat_dep = asinf(sin_lat);
    float num = c_lp * s_op;
    float den = c_lp * c_op * cos_p - s_lp * sin_p;
    float lon_dep = fmodf(lon_p + atan2f(num, den) + TWO_PI, TWO_PI);

    float xf = fmaf(lon_dep, X_SCALE, 2.0f);            // pix_x + PAD
    float yf = fmaf(lat_dep - MIN_LAT, Y_SCALE, 2.0f);  // pix_y + PAD

    float x0f = floorf(xf), txf = xf - x0f;
    float y0f = floorf(yf), tyf = yf - y0f;
    int ix0 = (int)x0f, iy0 = (int)y0f;
    float wx[4], wy[4];
    cubw(txf, wx);
    cubw(tyf, wy);

    const float* pv = projb + (size_t)vch * HW_;
    float acc = 0.f;
#pragma unroll
    for (int i = 0; i < 4; ++i) {
      int yi = iy0 - 1 + i;
      yi = yi < 0 ? 0 : (yi > HP_ - 1 ? HP_ - 1 : yi);
      int hh = yi - 2;
      int hs, sh = 0;
      if (hh < 0)        { hs = -1 - hh;         sh = 1; }
      else if (hh >= H_) { hs = 2 * H_ - 1 - hh; sh = 1; }
      else               { hs = hh; }
      const float* row = pv + hs * W_;
      int shoff = sh ? 180 : 0;
      float r = 0.f;
#pragma unroll
      for (int j = 0; j < 4; ++j) {
        int xi = ix0 - 1 + j;
        xi = xi < 0 ? 0 : (xi > WP_ - 1 ? WP_ - 1 : xi);
        int ww = xi - 2 + shoff;
        ww = ((ww % W_) + W_) % W_;
        r = fmaf(row[ww], wx[j], r);
      }
      acc = fmaf(r, wy[i], acc);
    }
    s2[vch] = f32x2{acc, acc};  // proj already includes down_b
  }

  // packed up-conv: 2 output channels per iteration
  float* ob = out + (size_t)b * C_ * HW_ + hw;
  const f32x2* up2 = (const f32x2*)upT2;        // [pair*8 + v]
  const f32x2* ub2 = (const f32x2*)up_b;        // bias pairs
  for (int i = 0; i < C_ / 2; ++i) {
    f32x2 o2 = ub2[i];
    const f32x2* uw = up2 + (size_t)i * 8;
#pragma unroll
    for (int v = 0; v < V_; ++v) o2 = __builtin_elementwise_fma(s2[v], uw[v], o2);
    ob[(size_t)(2 * i) * HW_] = o2.x;
    ob[(size_t)(2 * i + 1) * HW_] = o2.y;
  }
}

// ------------------------------------------------------------------
extern "C" void kernel_launch(void* const* d_in, const int* in_sizes, int n_in,
                              void* d_out, int out_size, void* d_ws,
                              size_t ws_size, hipStream_t stream) {
  const float* hidden = (const float*)d_in[0];
  const float* latg   = (const float*)d_in[1];
  const float* lonG   = (const float*)d_in[2];
  const float* dtp    = (const float*)d_in[3];
  const float* nsc    = (const float*)d_in[4];
  const float* nbi    = (const float*)d_in[5];
  const float* dwk    = (const float*)d_in[6];
  const float* dwb    = (const float*)d_in[7];
  const float* pw_w   = (const float*)d_in[8];
  const float* pw_b   = (const float*)d_in[9];
  const float* down_w = (const float*)d_in[10];
  const float* down_b = (const float*)d_in[11];
  const float* up_w   = (const float*)d_in[12];
  const float* up_b   = (const float*)d_in[13];
  float* out = (float*)d_out;

  float* ws    = (float*)d_ws;
  float* meanv = ws;                       // NP_
  float* rstdv = ws + NP_;                 // NP_
  float* vel   = ws + 2 * (size_t)NP_;     // 16*NP_
  float* proj  = ws + 18 * (size_t)NP_;    // 8*NP_
  float* vbias = ws + 26 * (size_t)NP_;    // 16
  float* kswt2 = vbias + 16;               // 192*18
  float* pwT2  = kswt2 + 192 * 18;         // 192*32
  float* upT2  = pwT2 + 192 * 32;          // 192*16

  int nblk = (NP_ + 255) / 256;
  hipLaunchKernelGGL(k_prep, dim3(1), dim3(C_), 0, stream, nsc, nbi, dwk, dwb,
                     pw_w, pw_b, up_w, vbias, kswt2, pwT2, upT2);
  hipLaunchKernelGGL(k_stats, dim3(nblk), dim3(256), 0, stream, hidden, down_w,
                     down_b, meanv, rstdv, proj);
  hipLaunchKernelGGL(k_vel, dim3(NWG_VEL), dim3(64), 0, stream, hidden, meanv,
                     rstdv, kswt2, pwT2, vel);
  hipLaunchKernelGGL(k_samp, dim3(nblk), dim3(256), 0, stream, vel, proj, latg,
                     lonG, dtp, upT2, up_b, vbias, out);
}

// Round 8
// 453.916 us; speedup vs baseline: 1.9686x; 1.1734x over previous
//
#include <hip/hip_runtime.h>
#include <math.h>
#include <cstdint>

#define B_ 4
#define C_ 384
#define V_ 8
#define H_ 181
#define W_ 360
#define HW_ (H_*W_)      // 65160
#define NP_ (B_*HW_)     // 260640
#define HP_ (H_+4)       // 185
#define WP_ (W_+4)       // 364

typedef float f32x2 __attribute__((ext_vector_type(2)));

// ------------------------------------------------------------------
// k_prep: fold biases; pair-interleaved weight tables.
// ------------------------------------------------------------------
__global__ void k_prep(const float* __restrict__ scale,
                       const float* __restrict__ bias,
                       const float* __restrict__ dwk,
                       const float* __restrict__ dwb,
                       const float* __restrict__ pw_w,
                       const float* __restrict__ pw_b,
                       const float* __restrict__ up_w,
                       float* __restrict__ vbias,
                       float* __restrict__ kswt2,
                       float* __restrict__ pwT2,
                       float* __restrict__ upT2) {
  __shared__ float sb[C_];
  int t = threadIdx.x;
  if (t < C_) {
    float ks = 0.f;
    float sc = scale[t];
    int pr = t >> 1, lo = t & 1;
#pragma unroll
    for (int k = 0; k < 9; ++k) {
      float kv = dwk[t * 9 + k];
      ks += kv;
      kswt2[pr * 18 + k * 2 + lo] = kv * sc;
    }
#pragma unroll
    for (int o = 0; o < 16; ++o) pwT2[pr * 32 + o * 2 + lo] = pw_w[o * C_ + t];
#pragma unroll
    for (int v = 0; v < 8; ++v) upT2[pr * 16 + v * 2 + lo] = up_w[t * V_ + v];
    sb[t] = bias[t] * ks + dwb[t];
  }
  __syncthreads();
  if (t < 16) {
    float acc = pw_b[t];
    for (int c = 0; c < C_; ++c) acc = fmaf(pw_w[t * C_ + c], sb[c], acc);
    vbias[t] = acc;
  }
}

// ------------------------------------------------------------------
// k_stats: LN mean/rstd per pixel + fused down-proj (raw x, 1x1 C->8)
// ------------------------------------------------------------------
__global__ __launch_bounds__(256) void k_stats(
    const float* __restrict__ x, const float* __restrict__ down_w,
    const float* __restrict__ down_b, float* __restrict__ meanv,
    float* __restrict__ rstdv, float* __restrict__ proj) {
  int p = blockIdx.x * 256 + threadIdx.x;
  if (p >= NP_) return;
  int b = p / HW_, hw = p - b * HW_;
  const float* xp = x + (size_t)b * C_ * HW_ + hw;

  float sA = 0.f, sB = 0.f, s2A = 0.f, s2B = 0.f;
  float apA[8], apB[8];
#pragma unroll
  for (int j = 0; j < 8; ++j) { apA[j] = 0.f; apB[j] = 0.f; }

#pragma unroll 4
  for (int c = 0; c < C_ / 2; ++c) {
    float v0 = xp[(size_t)c * HW_];
    float v1 = xp[(size_t)(c + C_ / 2) * HW_];
    sA += v0;
    sB += v1;
    s2A = fmaf(v0, v0, s2A);
    s2B = fmaf(v1, v1, s2B);
#pragma unroll
    for (int j = 0; j < 8; ++j) {
      apA[j] = fmaf(v0, down_w[j * C_ + c], apA[j]);
      apB[j] = fmaf(v1, down_w[j * C_ + c + C_ / 2], apB[j]);
    }
  }
  float m = (sA + sB) * (1.0f / C_);
  float var = fmaf(-m, m, (s2A + s2B) * (1.0f / C_));
  var = var < 0.f ? 0.f : var;
  meanv[p] = m;
  rstdv[p] = rsqrtf(var + 1e-5f);
#pragma unroll
  for (int j = 0; j < 8; ++j)
    proj[((size_t)b * 8 + j) * HW_ + hw] = apA[j] + apB[j] + down_b[j];
}

// ------------------------------------------------------------------
// k_vel: LN apply + geo-pad depthwise 3x3 + 1x1 (C->16) velocity.
// 256-thr blocks = 4 AUTONOMOUS waves (private LDS slices, 0 barriers).
// Each wave: 16x4 px tile, 18x6 halo, K-split half (192 ch, 12 chunks),
// register prefetch PINNED with sched_barrier(0). Packed f32 math.
// ------------------------------------------------------------------
#define BTW 16
#define BTH 16                      // 4 waves x 4 rows
#define WHW 18
#define WHH 6
#define WNH (WHW*WHH)               // 108
#define KP 8                        // channel pairs per chunk
#define KC (2*KP)                   // 16
#define CSPL 2
#define CPW (C_/CSPL)               // 192
#define NCH (CPW/KC)                // 12
#define NBX ((W_ + BTW - 1) / BTW)  // 23
#define NBY ((H_ + BTH - 1) / BTH)  // 12
#define NWG_VEL (NBX*NBY*B_*CSPL)   // 2208

__device__ __forceinline__ int geo_off_w(int h0, int w0, int i) {
  int hy = i / WHW, hx = i - hy * WHW;
  int hh = h0 - 1 + hy;
  int ww = w0 - 1 + hx;
  int hs, sh = 0;
  if (hh < 0)        { hs = -1 - hh;         sh = 180; }
  else if (hh >= H_) { hs = 2 * H_ - 1 - hh; sh = 180; }
  else               { hs = hh; }
  int ws2 = ww + sh;
  ws2 = ((ws2 % W_) + W_) % W_;
  return hs * W_ + ws2;
}

__global__ __launch_bounds__(256) void k_vel(
    const float* __restrict__ x, const float* __restrict__ meanv,
    const float* __restrict__ rstdv, const float* __restrict__ kswt2,
    const float* __restrict__ pwT2, float* __restrict__ velA,
    float* __restrict__ velB) {
  __shared__ f32x2 xn[4][KP][WNH];

  int tid = threadIdx.x;
  int wid = tid >> 6, lane = tid & 63;

  // bijective XCD swizzle: 2208 = 8 * 276; each XCD gets one (b,sl) plane
  int bid = blockIdx.x;
  int wg = (bid & 7) * (NWG_VEL / 8) + (bid >> 3);
  int bw = wg % NBX; wg /= NBX;
  int by = wg % NBY; wg /= NBY;
  int b  = wg % B_;
  int sl = wg / B_;
  int w0 = bw * BTW;
  int h0 = by * BTH + wid * 4;   // this wave's 4-row strip
  int cbase = sl * CPW;

  int i0 = lane, i1 = lane + 64;
  bool has1 = (i1 < WNH);  // lanes 0..43
  int o0 = geo_off_w(h0, w0, i0);
  int o1 = has1 ? geo_off_w(h0, w0, i1) : o0;

  size_t bHW = (size_t)b * HW_;
  float r0v = rstdv[bHW + o0];
  float n0v = -meanv[bHW + o0] * r0v;  // xn = x*r + n
  float r1v = rstdv[bHW + o1];
  float n1v = -meanv[bHW + o1] * r1v;
  f32x2 r0P = {r0v, r0v}, n0P = {n0v, n0v};
  f32x2 r1P = {r1v, r1v}, n1P = {n1v, n1v};

  const float* xb0 = x + ((size_t)b * C_ + cbase) * HW_ + o0;
  const float* xb1 = x + ((size_t)b * C_ + cbase) * HW_ + o1;

  f32x2 pf0[KP], pf1[KP];
#pragma unroll
  for (int k = 0; k < KP; ++k) {
    pf0[k].x = xb0[(size_t)(2 * k) * HW_];
    pf0[k].y = xb0[(size_t)(2 * k + 1) * HW_];
    pf1[k].x = xb1[(size_t)(2 * k) * HW_];
    pf1[k].y = xb1[(size_t)(2 * k + 1) * HW_];
  }

  int tx = lane & 15, ty = lane >> 4;
  f32x2 accP[16];
#pragma unroll
  for (int o = 0; o < 16; ++o) accP[o] = f32x2{0.f, 0.f};

  const f32x2* kk2 = (const f32x2*)kswt2;  // [pair*9 + tap]
  const f32x2* pw2 = (const f32x2*)pwT2;   // [pair*16 + o]
  f32x2 (*xw)[WNH] = xn[wid];              // this wave's private slice
  int pbase = cbase >> 1;                  // pair index base

#pragma unroll 1
  for (int chunk = 0; chunk < NCH - 1; ++chunk) {
    // ---- stage current chunk's normalized pairs into private LDS ----
#pragma unroll
    for (int k = 0; k < KP; ++k)
      xw[k][i0] = __builtin_elementwise_fma(pf0[k], r0P, n0P);
    if (has1) {
#pragma unroll
      for (int k = 0; k < KP; ++k)
        xw[k][i1] = __builtin_elementwise_fma(pf1[k], r1P, n1P);
    }

    // ---- issue next chunk's global loads (unconditional lanes) ----
    {
      const float* xc0 = xb0 + (size_t)(chunk + 1) * KC * HW_;
      const float* xc1 = xb1 + (size_t)(chunk + 1) * KC * HW_;
#pragma unroll
      for (int k = 0; k < KP; ++k) {
        pf0[k].x = xc0[(size_t)(2 * k) * HW_];
        pf0[k].y = xc0[(size_t)(2 * k + 1) * HW_];
        pf1[k].x = xc1[(size_t)(2 * k) * HW_];
        pf1[k].y = xc1[(size_t)(2 * k + 1) * HW_];
      }
    }
    // pin: loads may not sink below; compute may not hoist above
    __builtin_amdgcn_sched_barrier(0);

    // ---- compute current chunk ----
    int pc0 = pbase + chunk * KP;
#pragma unroll
    for (int kp = 0; kp < KP; ++kp) {
      const f32x2* kk = kk2 + (size_t)(pc0 + kp) * 9;   // wave-uniform
      const f32x2* pw = pw2 + (size_t)(pc0 + kp) * 16;  // wave-uniform
      f32x2 aP = {0.f, 0.f};
#pragma unroll
      for (int dy = 0; dy < 3; ++dy)
#pragma unroll
        for (int dx = 0; dx < 3; ++dx)
          aP = __builtin_elementwise_fma(xw[kp][(ty + dy) * WHW + tx + dx],
                                         kk[dy * 3 + dx], aP);
#pragma unroll
      for (int o = 0; o < 16; ++o)
        accP[o] = __builtin_elementwise_fma(aP, pw[o], accP[o]);
    }
  }

  // ---- last chunk: stage + compute (no prefetch) ----
#pragma unroll
  for (int k = 0; k < KP; ++k)
    xw[k][i0] = __builtin_elementwise_fma(pf0[k], r0P, n0P);
  if (has1) {
#pragma unroll
    for (int k = 0; k < KP; ++k)
      xw[k][i1] = __builtin_elementwise_fma(pf1[k], r1P, n1P);
  }
  {
    int pc0 = pbase + (NCH - 1) * KP;
#pragma unroll
    for (int kp = 0; kp < KP; ++kp) {
      const f32x2* kk = kk2 + (size_t)(pc0 + kp) * 9;
      const f32x2* pw = pw2 + (size_t)(pc0 + kp) * 16;
      f32x2 aP = {0.f, 0.f};
#pragma unroll
      for (int dy = 0; dy < 3; ++dy)
#pragma unroll
        for (int dx = 0; dx < 3; ++dx)
          aP = __builtin_elementwise_fma(xw[kp][(ty + dy) * WHW + tx + dx],
                                         kk[dy * 3 + dx], aP);
#pragma unroll
      for (int o = 0; o < 16; ++o)
        accP[o] = __builtin_elementwise_fma(aP, pw[o], accP[o]);
    }
  }

  int hp = h0 + ty, wp = w0 + tx;
  if (hp < H_ && wp < W_) {
    int hw = hp * W_ + wp;
    float* dst = sl ? (velB + (size_t)b * C_ * HW_ + hw)
                    : (velA + (size_t)b * 16 * HW_ + hw);
#pragma unroll
    for (int o = 0; o < 16; ++o)
      dst[(size_t)o * HW_] = accP[o].x + accP[o].y;
  }
}

// ------------------------------------------------------------------
// k_samp: departure points + bicubic geo-sample + packed 1x1 up (8->384)
// vel = velA (ws) + velB (d_out channels 0..15, read before overwrite)
// ------------------------------------------------------------------
__device__ __forceinline__ void cubw(float t, float w[4]) {
  const float A = -0.75f;
  float t1 = t + 1.0f;
  w[0] = ((A * t1 - 5.0f * A) * t1 + 8.0f * A) * t1 - 4.0f * A;
  w[1] = ((A + 2.0f) * t - (A + 3.0f)) * t * t + 1.0f;
  float s = 1.0f - t;
  w[2] = ((A + 2.0f) * s - (A + 3.0f)) * s * s + 1.0f;
  float t2 = 2.0f - t;
  w[3] = ((A * t2 - 5.0f * A) * t2 + 8.0f * A) * t2 - 4.0f * A;
}

__global__ __launch_bounds__(256) void k_samp(
    const float* __restrict__ velA, const float* __restrict__ proj,
    const float* __restrict__ latg, const float* __restrict__ lonG,
    const float* __restrict__ dtp, const float* __restrict__ upT2,
    const float* __restrict__ up_b, const float* __restrict__ vbias,
    float* out) {
  int p = blockIdx.x * 256 + threadIdx.x;
  if (p >= NP_) return;
  int b = p / HW_, hw = p - b * HW_;

  const float TWO_PI = 6.28318530717958647692f;
  const float X_SCALE = 57.295779513082320877f;  // W/(2*pi)
  const float MIN_LAT = -1.57079632679489661923f;
  const float Y_SCALE = 57.295779513082320877f;  // (H-1)/pi

  float dt = dtp[0];
  float lat_p = latg[p];
  float lon_p = lonG[p];
  float sin_p, cos_p;
  sincosf(lat_p, &sin_p, &cos_p);

  f32x2 s2[V_];
  const float* projb = proj + (size_t)b * V_ * HW_;
  const float* vA = velA + (size_t)b * 16 * HW_ + hw;
  const float* vB = out + (size_t)b * C_ * HW_ + hw;  // partials in ch 0..15

  for (int vch = 0; vch < V_; ++vch) {
    float u  = vA[(size_t)vch * HW_] + vB[(size_t)vch * HW_] + vbias[vch];
    float vv = vA[(size_t)(8 + vch) * HW_] + vB[(size_t)(8 + vch) * HW_] +
               vbias[8 + vch];
    float lon_pr = -u * dt;
    float lat_pr = -vv * dt;
    float s_lp, c_lp, s_op, c_op;
    sincosf(lat_pr, &s_lp, &c_lp);
    sincosf(lon_pr, &s_op, &c_op);
    float sin_lat = s_lp * cos_p + c_lp * c_op * sin_p;
    sin_lat = fminf(fmaxf(sin_lat, -1.0f + 1e-7f), 1.0f - 1e-7f);
    float lat_dep = asinf(sin_lat);
    float num = c_lp * s_op;
    float den = c_lp * c_op * cos_p - s_lp * sin_p;
    float lon_dep = fmodf(lon_p + atan2f(num, den) + TWO_PI, TWO_PI);

    float xf = fmaf(lon_dep, X_SCALE, 2.0f);            // pix_x + PAD
    float yf = fmaf(lat_dep - MIN_LAT, Y_SCALE, 2.0f);  // pix_y + PAD

    float x0f = floorf(xf), txf = xf - x0f;
    float y0f = floorf(yf), tyf = yf - y0f;
    int ix0 = (int)x0f, iy0 = (int)y0f;
    float wx[4], wy[4];
    cubw(txf, wx);
    cubw(tyf, wy);

    const float* pv = projb + (size_t)vch * HW_;
    float acc = 0.f;
#pragma unroll
    for (int i = 0; i < 4; ++i) {
      int yi = iy0 - 1 + i;
      yi = yi < 0 ? 0 : (yi > HP_ - 1 ? HP_ - 1 : yi);
      int hh = yi - 2;
      int hs, sh = 0;
      if (hh < 0)        { hs = -1 - hh;         sh = 1; }
      else if (hh >= H_) { hs = 2 * H_ - 1 - hh; sh = 1; }
      else               { hs = hh; }
      const float* row = pv + hs * W_;
      int shoff = sh ? 180 : 0;
      float r = 0.f;
#pragma unroll
      for (int j = 0; j < 4; ++j) {
        int xi = ix0 - 1 + j;
        xi = xi < 0 ? 0 : (xi > WP_ - 1 ? WP_ - 1 : xi);
        int ww = xi - 2 + shoff;
        ww = ((ww % W_) + W_) % W_;
        r = fmaf(row[ww], wx[j], r);
      }
      acc = fmaf(r, wy[i], acc);
    }
    s2[vch] = f32x2{acc, acc};  // proj already includes down_b
  }

  // packed up-conv: 2 output channels per iteration
  float* ob = out + (size_t)b * C_ * HW_ + hw;
  const f32x2* up2 = (const f32x2*)upT2;        // [pair*8 + v]
  const f32x2* ub2 = (const f32x2*)up_b;        // bias pairs
  for (int i = 0; i < C_ / 2; ++i) {
    f32x2 o2 = ub2[i];
    const f32x2* uw = up2 + (size_t)i * 8;
#pragma unroll
    for (int v = 0; v < V_; ++v) o2 = __builtin_elementwise_fma(s2[v], uw[v], o2);
    ob[(size_t)(2 * i) * HW_] = o2.x;
    ob[(size_t)(2 * i + 1) * HW_] = o2.y;
  }
}

// ------------------------------------------------------------------
extern "C" void kernel_launch(void* const* d_in, const int* in_sizes, int n_in,
                              void* d_out, int out_size, void* d_ws,
                              size_t ws_size, hipStream_t stream) {
  const float* hidden = (const float*)d_in[0];
  const float* latg   = (const float*)d_in[1];
  const float* lonG   = (const float*)d_in[2];
  const float* dtp    = (const float*)d_in[3];
  const float* nsc    = (const float*)d_in[4];
  const float* nbi    = (const float*)d_in[5];
  const float* dwk    = (const float*)d_in[6];
  const float* dwb    = (const float*)d_in[7];
  const float* pw_w   = (const float*)d_in[8];
  const float* pw_b   = (const float*)d_in[9];
  const float* down_w = (const float*)d_in[10];
  const float* down_b = (const float*)d_in[11];
  const float* up_w   = (const float*)d_in[12];
  const float* up_b   = (const float*)d_in[13];
  float* out = (float*)d_out;

  float* ws    = (float*)d_ws;
  float* meanv = ws;                       // NP_
  float* rstdv = ws + NP_;                 // NP_
  float* velA  = ws + 2 * (size_t)NP_;     // 16*NP_
  float* proj  = ws + 18 * (size_t)NP_;    // 8*NP_
  float* vbias = ws + 26 * (size_t)NP_;    // 16
  float* kswt2 = vbias + 16;               // 192*18
  float* pwT2  = kswt2 + 192 * 18;         // 192*32
  float* upT2  = pwT2 + 192 * 32;          // 192*16

  int nblk = (NP_ + 255) / 256;
  hipLaunchKernelGGL(k_prep, dim3(1), dim3(C_), 0, stream, nsc, nbi, dwk, dwb,
                     pw_w, pw_b, up_w, vbias, kswt2, pwT2, upT2);
  hipLaunchKernelGGL(k_stats, dim3(nblk), dim3(256), 0, stream, hidden, down_w,
                     down_b, meanv, rstdv, proj);
  hipLaunchKernelGGL(k_vel, dim3(NWG_VEL), dim3(256), 0, stream, hidden, meanv,
                     rstdv, kswt2, pwT2, velA, out);
  hipLaunchKernelGGL(k_samp, dim3(nblk), dim3(256), 0, stream, velA, proj,
                     latg, lonG, dtp, upT2, up_b, vbias, out);
}